// Round 12
// baseline (399.809 us; speedup 1.0000x reference)
//
#include <hip/hip_runtime.h>
#include <stdint.h>

// Problem: B=8, L=4096, D=256, K=4096
#define NROWS 32768
#define KC 4096
#define DIM 256
#define BM 64            // rows per block (2 row-tiles of 32)
#define TPS 64           // col-tiles per stream (2 streams x 64 = 128)
#define CAP 40
#define KAPPA 0.99960f   // exp(-margin), margin 4e-4 > validated 3e-4
#define K2L2E 2.88539008f // 2*log2(e)
#define L2E 1.44269504f

#define OUT_IDX (NROWS * DIM)
#define OUT_SCAL (OUT_IDX + NROWS)

// Workspace layout (bytes)
#define WS_CNORM 0
#define WS_ZNORM 16384
#define WS_LOSS  147456
#define WS_AVGP8 147712                  // 8 shadows x 4096 f32 = 128 KB
#define WS_FRAG  278784                  // bf16 fragment image, 2 MB

typedef __bf16 bf8 __attribute__((ext_vector_type(8)));
typedef float f16v __attribute__((ext_vector_type(16)));

// async global->LDS, 16B per lane; LDS dest = wave-uniform base + lane*16
#define GLOAD_LDS(g, l) \
  __builtin_amdgcn_global_load_lds( \
      (const __attribute__((address_space(1))) void*)(g), \
      (__attribute__((address_space(3))) void*)(l), 16, 0, 0)

// monotonic float->uint order map (argmin with first-index tie-break)
__device__ __forceinline__ unsigned ford(float f) {
  unsigned u = __float_as_uint(f);
  return (u & 0x80000000u) ? ~u : (u | 0x80000000u);
}

// numpy pairwise-sum of x**2 (n=256), bitwise == np.sum(x**2).
// Same arithmetic/order as the validated scalar version; loads via float4.
__device__ __forceinline__ float np_rownorm256(const float* __restrict__ p) {
  float h[2];
  #pragma unroll
  for (int half = 0; half < 2; ++half) {
    const float* b = p + half * 128;
    float r[8];
    {
      float4 v0 = *(const float4*)(b);
      float4 v1 = *(const float4*)(b + 4);
      r[0] = __fmul_rn(v0.x, v0.x); r[1] = __fmul_rn(v0.y, v0.y);
      r[2] = __fmul_rn(v0.z, v0.z); r[3] = __fmul_rn(v0.w, v0.w);
      r[4] = __fmul_rn(v1.x, v1.x); r[5] = __fmul_rn(v1.y, v1.y);
      r[6] = __fmul_rn(v1.z, v1.z); r[7] = __fmul_rn(v1.w, v1.w);
    }
    for (int i = 8; i < 128; i += 8) {
      float4 v0 = *(const float4*)(b + i);
      float4 v1 = *(const float4*)(b + i + 4);
      r[0] = __fadd_rn(r[0], __fmul_rn(v0.x, v0.x));
      r[1] = __fadd_rn(r[1], __fmul_rn(v0.y, v0.y));
      r[2] = __fadd_rn(r[2], __fmul_rn(v0.z, v0.z));
      r[3] = __fadd_rn(r[3], __fmul_rn(v0.w, v0.w));
      r[4] = __fadd_rn(r[4], __fmul_rn(v1.x, v1.x));
      r[5] = __fadd_rn(r[5], __fmul_rn(v1.y, v1.y));
      r[6] = __fadd_rn(r[6], __fmul_rn(v1.z, v1.z));
      r[7] = __fadd_rn(r[7], __fmul_rn(v1.w, v1.w));
    }
    h[half] = __fadd_rn(
        __fadd_rn(__fadd_rn(r[0], r[1]), __fadd_rn(r[2], r[3])),
        __fadd_rn(__fadd_rn(r[4], r[5]), __fadd_rn(r[6], r[7])));
  }
  return __fadd_rn(h[0], h[1]);
}

__global__ void k_norms(const float* __restrict__ cbw, const float* __restrict__ z,
                        float* __restrict__ cnorm, float* __restrict__ znorm) {
  int r = blockIdx.x * 256 + threadIdx.x;
  if (r < KC) cnorm[r] = np_rownorm256(cbw + (size_t)r * DIM);
  else {
    int q = r - KC;
    if (q < NROWS) znorm[q] = np_rownorm256(z + (size_t)q * DIM);
  }
}

// Build bf16 B-fragment image: frag[ct][ds][lane][8] with
// frag(...)[j] = bf16(cb[ct*32 + (lane&31)][ds*16 + (lane>>5)*8 + j])
__global__ void k_frag(const float* __restrict__ cbw, __bf16* __restrict__ frag) {
  int idx = blockIdx.x * 256 + threadIdx.x;   // 131072 units of 16B
  int c = idx >> 5, u = idx & 31;
  int ds = u >> 1, half = u & 1;
  int ct = c >> 5, m = c & 31;
  int lane = half * 32 + m;
  const float* src = cbw + (size_t)c * DIM + ds * 16 + half * 8;
  float4 a = *(const float4*)src;
  float4 b = *(const float4*)(src + 4);
  bf8 h;
  h[0] = (__bf16)a.x; h[1] = (__bf16)a.y; h[2] = (__bf16)a.z; h[3] = (__bf16)a.w;
  h[4] = (__bf16)b.x; h[5] = (__bf16)b.y; h[6] = (__bf16)b.z; h[7] = (__bf16)b.w;
  *(bf8*)(frag + ((size_t)(ct * 16 + ds) * 64 + lane) * 8) = h;
}

// np-bitwise d2 (validated): sequential fmaf chain, d2 = fl(fl(rn+cn)-fl(2*mm))
__device__ __forceinline__ float exact_d2(const float* __restrict__ zr,
                                          const float* __restrict__ cr,
                                          float rn, float cn) {
  float mm = 0.f;
  for (int d = 0; d < DIM; d += 4) {
    float4 zv = *(const float4*)(zr + d);
    float4 cv = *(const float4*)(cr + d);
    mm = __builtin_fmaf(zv.x, cv.x, mm);
    mm = __builtin_fmaf(zv.y, cv.y, mm);
    mm = __builtin_fmaf(zv.z, cv.z, mm);
    mm = __builtin_fmaf(zv.w, cv.w, mm);
  }
  return __fsub_rn(__fadd_rn(rn, cn), __fmul_rn(2.f, mm));
}

// B-tile load helper (LDS, bf16 elems)
#define BLD(bs, c) (*(const bf8*)((bs) + (c) * 512 + lane * 8))

// A-fragment registers: 16 named bf8 (64 VGPR), hoisted once per kernel
#define AQ_ALL(OP) OP(0) OP(1) OP(2) OP(3) OP(4) OP(5) OP(6) OP(7) \
                   OP(8) OP(9) OP(10) OP(11) OP(12) OP(13) OP(14) OP(15)
#define AQ_DECL(i) const bf8 aq##i = \
  *(const bf8*)&BstA[((size_t)(wr * 16 + (i)) * 64 + lane) * 8];

#define MF2(ACC, A, B) ACC = __builtin_amdgcn_mfma_f32_32x32x16_bf16((A), (B), ACC, 0, 0, 0);
#define CONS16(ACC, bs_) { \
  __builtin_amdgcn_s_setprio(1); \
  MF2(ACC, aq0,  BLD(bs_,0))  MF2(ACC, aq1,  BLD(bs_,1))  \
  MF2(ACC, aq2,  BLD(bs_,2))  MF2(ACC, aq3,  BLD(bs_,3))  \
  MF2(ACC, aq4,  BLD(bs_,4))  MF2(ACC, aq5,  BLD(bs_,5))  \
  MF2(ACC, aq6,  BLD(bs_,6))  MF2(ACC, aq7,  BLD(bs_,7))  \
  MF2(ACC, aq8,  BLD(bs_,8))  MF2(ACC, aq9,  BLD(bs_,9))  \
  MF2(ACC, aq10, BLD(bs_,10)) MF2(ACC, aq11, BLD(bs_,11)) \
  MF2(ACC, aq12, BLD(bs_,12)) MF2(ACC, aq13, BLD(bs_,13)) \
  MF2(ACC, aq14, BLD(bs_,14)) MF2(ACC, aq15, BLD(bs_,15)) \
  __builtin_amdgcn_s_setprio(0); }

#define ZERO16(ACC) { _Pragma("unroll") \
  for (int r_ = 0; r_ < 16; ++r_) ACC[r_] = 0.f; }

// 256 threads, 4 waves = 2 row-tiles x 2 streams, 2 blocks/CU (~77 KB LDS).
// R11 (+6.5%) proved the scheduling basin; R12 adds the T15 deferred epilogue:
// dual accumulators, tile t-1's exp2/filter epilogue (VALU pipe) interleaved
// with tile t's ds_read+MFMA chain (LDS+matrix pipes). Epilogue ORDER is
// unchanged (slot-shifted) -> identical es fl-chains; rowmax snapshots are
// fresher lower bounds -> still a superset filter; exact rescore unchanged.
__global__ __launch_bounds__(256, 2) void k_main(
    const float* __restrict__ z, const float* __restrict__ cbw,
    const float* __restrict__ cnorm, const float* __restrict__ znorm,
    const __bf16* __restrict__ frag, float* __restrict__ out,
    float* __restrict__ avgp8, double* __restrict__ losssum) {
  // Two DISTINCT double-buffer halves (16 KB per stream each).
  // BstX doubles as the A-stage bounce (32 KB) before the sweep.
  __shared__ __attribute__((aligned(16))) __bf16 BstX[2][8192];        // 32 KB
  __shared__ __attribute__((aligned(16))) __bf16 BstY[2][8192];        // 32 KB
  __shared__ int cand[BM][CAP];                                        // 10 KB
  __shared__ int ccount[BM];
  __shared__ unsigned rowmaxU[BM];                 // running max of e (exp dom)
  __shared__ unsigned long long rowkey[BM];
  __shared__ float esumL[BM], invR[BM], lred[256];
  __shared__ int idxr[BM];

  const int t = threadIdx.x;
  const int lane = t & 63, wv = t >> 6;
  const int ln31 = lane & 31, lh = lane >> 5;
  const int wr = wv >> 1, wc = wv & 1;    // row-tile, column-stream
  const int row0 = blockIdx.x * BM;
  const int ctbase = wc * TPS;

  if (t < BM) {
    ccount[t] = 0; rowmaxU[t] = 0u; rowkey[t] = ~0ULL; esumL[t] = 0.f;
  }

  // ---- stage A (rows 0..63) frag image into BstX cooperatively ----
  __bf16* BstA = &BstX[0][0];
  #pragma unroll
  for (int i = 0; i < 8; ++i) {
    int idx = i * 256 + t;            // 2048 units of 16B
    int l = idx & 63, ds = (idx >> 6) & 15, rt = idx >> 10;
    int row = rt * 32 + (l & 31), d0 = ds * 16 + (l >> 5) * 8;
    const float* src = z + (size_t)(row0 + row) * DIM + d0;
    float4 a = *(const float4*)src;
    float4 b = *(const float4*)(src + 4);
    bf8 h;
    h[0] = (__bf16)a.x; h[1] = (__bf16)a.y; h[2] = (__bf16)a.z; h[3] = (__bf16)a.w;
    h[4] = (__bf16)b.x; h[5] = (__bf16)b.y; h[6] = (__bf16)b.z; h[7] = (__bf16)b.w;
    *(bf8*)&BstA[((size_t)((rt * 16 + ds) * 64 + l)) * 8] = h;
  }
  __syncthreads();

  // ---- hoist A fragments to registers, then BstX/BstY are B buffers ----
  AQ_ALL(AQ_DECL)
  __syncthreads();

  // stage the FULL 16KB B tile ct into ARR[wc]: this wave issues its 8KB
  // share (8 x global_load_lds); the stream's 2 row-waves cover the tile.
  #define STG_A(ARR, ct) { \
    const char* g_ = (const char*)frag + (size_t)(ct) * 16384 + wr * 8192 \
                     + (size_t)lane * 16; \
    char* l_ = (char*)(&ARR[wc][0]) + wr * 8192; \
    GLOAD_LDS(g_, l_);               GLOAD_LDS(g_ + 1024, l_ + 1024); \
    GLOAD_LDS(g_ + 2048, l_ + 2048); GLOAD_LDS(g_ + 3072, l_ + 3072); \
    GLOAD_LDS(g_ + 4096, l_ + 4096); GLOAD_LDS(g_ + 5120, l_ + 5120); \
    GLOAD_LDS(g_ + 6144, l_ + 6144); GLOAD_LDS(g_ + 7168, l_ + 7168); \
  }
  #define XP ((const __bf16*)&BstX[wc][0])
  #define YP ((const __bf16*)&BstY[wc][0])

  float es[16];
  #pragma unroll
  for (int i = 0; i < 16; ++i) es[i] = 0.f;

  // prime epilogue: seed shared row max (both streams seed each row)
  #define PRIME_EPI(ACC, ctv) { \
    const float cnl = cnorm[(ctv) * 32 + ln31] * L2E; \
    _Pragma("unroll") \
    for (int r = 0; r < 16; ++r) { \
      const int row = wr * 32 + (r & 3) + 8 * (r >> 2) + 4 * lh; \
      float e = exp2f(__builtin_fmaf(ACC[r], K2L2E, -cnl)); \
      atomicMax(&rowmaxU[row], __float_as_uint(e));  /* e>0: order-preserving */ \
    } \
  }

  // branchless sweep epilogue (R11-validated): snapshot is a lower bound of
  // the true row max -> superset candidate filter; exact rescore fixes all.
  #define SWEEP_EPI(ACC, ctv) { \
    const float cnl = cnorm[(ctv) * 32 + ln31] * L2E; \
    float cr[16]; \
    { \
      const float4* rmf = (const float4*)(rowmaxU + wr * 32); \
      float4 c0 = rmf[lh], c1 = rmf[2 + lh], c2 = rmf[4 + lh], c3 = rmf[6 + lh]; \
      cr[0]  = c0.x; cr[1]  = c0.y; cr[2]  = c0.z; cr[3]  = c0.w; \
      cr[4]  = c1.x; cr[5]  = c1.y; cr[6]  = c1.z; cr[7]  = c1.w; \
      cr[8]  = c2.x; cr[9]  = c2.y; cr[10] = c2.z; cr[11] = c2.w; \
      cr[12] = c3.x; cr[13] = c3.y; cr[14] = c3.z; cr[15] = c3.w; \
    } \
    unsigned cond = 0u; \
    _Pragma("unroll") \
    for (int r = 0; r < 16; ++r) { \
      float e = exp2f(__builtin_fmaf(ACC[r], K2L2E, -cnl)); \
      es[r] += e;                       /* per-wave sequential fl-chain */ \
      cond |= (e >= cr[r] * KAPPA) ? (1u << r) : 0u; \
    } \
    if (cond) {   /* rare exec-masked slow path: refresh max + insert */ \
      _Pragma("unroll") \
      for (int r = 0; r < 16; ++r) { \
        if (cond & (1u << r)) { \
          const int row = wr * 32 + (r & 3) + 8 * (r >> 2) + 4 * lh; \
          float e = exp2f(__builtin_fmaf(ACC[r], K2L2E, -cnl)); \
          atomicMax(&rowmaxU[row], __float_as_uint(e)); \
          int slot = atomicAdd(&ccount[row], 1); \
          if (slot < CAP) cand[row][slot] = (ctv) * 32 + ln31; \
        } \
      } \
    } \
  }

  // ===== Phase 1: 65 slots (prime c0 + sweep 0..63), deferred epilogue =====
  // Slot s consumes tile T1(s) (T1(0)=ctbase, T1(s)=ctbase+s-1), stages
  // T1(s+1) into the other buffer, and runs the EPILOGUE OF SLOT s-1 (whose
  // acc is in the other accumulator) interleaved with this slot's MFMA chain.
  {
    f16v accU, accV;
    STG_A(BstX, ctbase)                    // T1(0) -> X
    __syncthreads();
    // slot 0: CONS c0 (prime tile) from X; stage T1(1)=ctbase -> Y; no EPI
    STG_A(BstY, ctbase)
    ZERO16(accU) CONS16(accU, XP)
    __syncthreads();
    // slot 1: CONS sweep-0 (ct=ctbase) from Y; stage ctbase+1 -> X; PRIME(accU)
    STG_A(BstX, ctbase + 1)
    ZERO16(accV) CONS16(accV, YP)
    PRIME_EPI(accU, ctbase)
    __syncthreads();
    // slot 2: CONS sweep-1 from X; stage ctbase+2 -> Y; SWEEP(accV, ctbase+0)
    STG_A(BstY, ctbase + 2)
    ZERO16(accU) CONS16(accU, XP)
    SWEEP_EPI(accV, ctbase)
    __syncthreads();
    for (int p = 1; p < 32; ++p) {
      // slot 2p+1: CONS from Y; stage ctbase+2p+1 -> X; EPI(accU, ctbase+2p-1)
      STG_A(BstX, ctbase + 2 * p + 1)
      ZERO16(accV) CONS16(accV, YP)
      SWEEP_EPI(accU, ctbase + 2 * p - 1)
      __syncthreads();
      // slot 2p+2: CONS from X; stage next -> Y (tail clamp); EPI(accV, ctbase+2p)
      {
        const int nx = (2 * p + 2 <= 63) ? (ctbase + 2 * p + 2) : (ctbase + 63);
        STG_A(BstY, nx)
      }
      ZERO16(accU) CONS16(accU, XP)
      SWEEP_EPI(accV, ctbase + 2 * p)
      __syncthreads();
    }
    // final epilogue: slot 64's tile (ct = ctbase+63) in accU
    SWEEP_EPI(accU, ctbase + 63)
  }

  // ---- row exp-sum reduction (32 lanes of same half share rows) ----
  #pragma unroll
  for (int r = 0; r < 16; ++r) {
    float e = es[r];
    #pragma unroll
    for (int off = 16; off > 0; off >>= 1) e += __shfl_xor(e, off);
    if (ln31 == 0) {
      const int row = wr * 32 + (r & 3) + 8 * (r >> 2) + 4 * lh;
      atomicAdd(&esumL[row], e);
    }
  }
  __syncthreads();
  if (t < BM) invR[t] = 1.0f / esumL[t];
  __syncthreads();

  // ---- exact np-bitwise rescore of candidates -> argmin (4 threads/row) ----
  {
    int r = t & 63, q = t >> 6;   // q in 0..3
    int cnt = ccount[r];
    const float* zr = z + (size_t)(row0 + r) * DIM;
    float rn = znorm[row0 + r];
    if (cnt <= CAP) {
      for (int s = q; s < cnt; s += 4) {
        int k = cand[r][s];
        float d2 = exact_d2(zr, cbw + (size_t)k * DIM, rn, cnorm[k]);
        atomicMin(&rowkey[r], (((unsigned long long)ford(d2)) << 32) | (unsigned)k);
      }
    } else {  // overflow (improbable): full exact scan, still correct
      for (int k = q; k < KC; k += 4) {
        float d2 = exact_d2(zr, cbw + (size_t)k * DIM, rn, cnorm[k]);
        atomicMin(&rowkey[r], (((unsigned long long)ford(d2)) << 32) | (unsigned)k);
      }
    }
  }
  __syncthreads();
  if (t < BM) {
    int idx = (int)(rowkey[t] & 0xFFFFFFFFULL);
    idxr[t] = idx;
    out[OUT_IDX + row0 + t] = (float)idx;
  }
  __syncthreads();

  // ---- z_q gather, STE output, loss partial (256 threads = 256 cols) ----
  float lacc = 0.f;
  for (int r = 0; r < BM; ++r) {
    int idx = idxr[r];
    float zq = cbw[(size_t)idx * DIM + t];
    float zv = z[(size_t)(row0 + r) * DIM + t];
    float df = __fsub_rn(zq, zv);
    out[(size_t)(row0 + r) * DIM + t] = __fadd_rn(zv, df);
    lacc += df * df;
  }
  lred[t] = lacc;
  __syncthreads();
  #pragma unroll
  for (int s = 128; s > 0; s >>= 1) {
    if (t < s) lred[t] += lred[t + s];
    __syncthreads();
  }
  if (t == 0) atomicAdd(losssum, (double)lred[0]);

  // ---- invR to regs for phase 2 ----
  float ir[16];
  #pragma unroll
  for (int r = 0; r < 16; ++r)
    ir[r] = invR[wr * 32 + (r & 3) + 8 * (r >> 2) + 4 * lh];
  __syncthreads();

  // phase-2 epilogue: avg_probs partial per col (deferred one slot)
  #define P2EPI(ACC, ctv) { \
    const float cnl = cnorm[(ctv) * 32 + ln31] * L2E; \
    float s2 = 0.f; \
    _Pragma("unroll") \
    for (int r = 0; r < 16; ++r) { \
      float e = exp2f(__builtin_fmaf(ACC[r], K2L2E, -cnl)); \
      s2 = __builtin_fmaf(e, ir[r], s2); \
    } \
    s2 += __shfl_xor(s2, 32);           /* merge the two lh halves */ \
    if (lh == 0) atomicAdd(&shadow[(ctv) * 32 + ln31], s2); \
  }

  // ===== Phase 2: 64 slots (tiles ctbase+0..63), deferred epilogue =====
  {
    float* shadow = avgp8 + (size_t)(blockIdx.x & 7) * KC;
    f16v accU, accV;
    STG_A(BstX, ctbase)                    // t0 -> X
    __syncthreads();
    // slot 0: CONS t0 from X; stage t1 -> Y; no EPI
    STG_A(BstY, ctbase + 1)
    ZERO16(accU) CONS16(accU, XP)
    __syncthreads();
    for (int p = 0; p < 31; ++p) {
      // slot 2p+1: CONS t_{2p+1} from Y; stage t_{2p+2} -> X; EPI(accU, t_{2p})
      STG_A(BstX, ctbase + 2 * p + 2)
      ZERO16(accV) CONS16(accV, YP)
      P2EPI(accU, ctbase + 2 * p)
      __syncthreads();
      // slot 2p+2: CONS t_{2p+2} from X; stage t_{2p+3} -> Y; EPI(accV, t_{2p+1})
      STG_A(BstY, ctbase + 2 * p + 3)
      ZERO16(accU) CONS16(accU, XP)
      P2EPI(accV, ctbase + 2 * p + 1)
      __syncthreads();
    }
    // slot 63: CONS t63 from Y; EPI(accU, t62); then final EPI(accV, t63)
    ZERO16(accV) CONS16(accV, YP)
    P2EPI(accU, ctbase + 62)
    P2EPI(accV, ctbase + 63)
  }
}

__global__ void k_final(const float* __restrict__ avgp8,
                        const double* __restrict__ losssum,
                        float* __restrict__ out) {
  const int t = threadIdx.x;
  double part = 0.0;
  for (int k = t; k < KC; k += 256) {
    float a4 = 0.f;
    #pragma unroll
    for (int s = 0; s < 8; ++s) a4 += avgp8[s * KC + k];
    double a = (double)a4 / (double)NROWS;
    part += a * log(a + 1e-10);
  }
  __shared__ double sd[256];
  sd[t] = part;
  __syncthreads();
  for (int s = 128; s > 0; s >>= 1) {
    if (t < s) sd[t] += sd[t + s];
    __syncthreads();
  }
  if (t == 0) {
    double H = -sd[0];
    double mse = losssum[0] / (double)((size_t)NROWS * DIM);
    double ccl = 1.25 * mse;
    double sel = -0.1 * H;
    out[OUT_SCAL + 0] = (float)(ccl + sel);
    out[OUT_SCAL + 1] = (float)ccl;
    out[OUT_SCAL + 2] = (float)sel;
  }
}

extern "C" void kernel_launch(void* const* d_in, const int* in_sizes, int n_in,
                              void* d_out, int out_size, void* d_ws, size_t ws_size,
                              hipStream_t stream) {
  const float* z = (const float*)d_in[0];
  const float* cbw = (const float*)d_in[1];
  float* out = (float*)d_out;
  char* ws = (char*)d_ws;
  float* cnorm = (float*)(ws + WS_CNORM);
  float* znorm = (float*)(ws + WS_ZNORM);
  double* losssum = (double*)(ws + WS_LOSS);
  float* avgp8 = (float*)(ws + WS_AVGP8);
  __bf16* frag = (__bf16*)(ws + WS_FRAG);

  hipMemsetAsync(ws + WS_LOSS, 0, 8, stream);
  hipMemsetAsync(ws + WS_AVGP8, 0, 8 * KC * 4, stream);
  k_norms<<<(KC + NROWS) / 256, 256, 0, stream>>>(cbw, z, cnorm, znorm);
  k_frag<<<(KC * 32) / 256, 256, 0, stream>>>(cbw, frag);
  k_main<<<NROWS / BM, 256, 0, stream>>>(z, cbw, cnorm, znorm, frag, out,
                                         avgp8, losssum);
  k_final<<<1, 256, 0, stream>>>(avgp8, losssum, out);
}

// Round 15
// 395.873 us; speedup vs baseline: 1.0099x; 1.0099x over previous
//
#include <hip/hip_runtime.h>
#include <stdint.h>

// Problem: B=8, L=4096, D=256, K=4096
#define NROWS 32768
#define KC 4096
#define DIM 256
#define BM 64            // rows per block (2 row-tiles of 32)
#define TPS 64           // col-tiles per stream (2 streams x 64 = 128)
#define CAP 40
#define KAPPA 0.99960f   // exp(-margin), margin 4e-4 > validated 3e-4
#define K2L2E 2.88539008f // 2*log2(e)
#define L2E 1.44269504f

#define OUT_IDX (NROWS * DIM)
#define OUT_SCAL (OUT_IDX + NROWS)

// Workspace layout (bytes)
#define WS_CNORM 0
#define WS_ZNORM 16384
#define WS_LOSS  147456
#define WS_AVGP8 147712                  // 8 shadows x 4096 f32 = 128 KB
#define WS_FRAG  278784                  // bf16 fragment image, 2 MB

typedef __bf16 bf8 __attribute__((ext_vector_type(8)));
typedef float f16v __attribute__((ext_vector_type(16)));

// async global->LDS, 16B per lane; LDS dest = wave-uniform base + lane*16
#define GLOAD_LDS(g, l) \
  __builtin_amdgcn_global_load_lds( \
      (const __attribute__((address_space(1))) void*)(g), \
      (__attribute__((address_space(3))) void*)(l), 16, 0, 0)

// monotonic float->uint order map (argmin with first-index tie-break)
__device__ __forceinline__ unsigned ford(float f) {
  unsigned u = __float_as_uint(f);
  return (u & 0x80000000u) ? ~u : (u | 0x80000000u);
}

// numpy pairwise-sum of x**2 (n=256), bitwise == np.sum(x**2).
// Same arithmetic/order as the validated scalar version; loads via float4.
__device__ __forceinline__ float np_rownorm256(const float* __restrict__ p) {
  float h[2];
  #pragma unroll
  for (int half = 0; half < 2; ++half) {
    const float* b = p + half * 128;
    float r[8];
    {
      float4 v0 = *(const float4*)(b);
      float4 v1 = *(const float4*)(b + 4);
      r[0] = __fmul_rn(v0.x, v0.x); r[1] = __fmul_rn(v0.y, v0.y);
      r[2] = __fmul_rn(v0.z, v0.z); r[3] = __fmul_rn(v0.w, v0.w);
      r[4] = __fmul_rn(v1.x, v1.x); r[5] = __fmul_rn(v1.y, v1.y);
      r[6] = __fmul_rn(v1.z, v1.z); r[7] = __fmul_rn(v1.w, v1.w);
    }
    for (int i = 8; i < 128; i += 8) {
      float4 v0 = *(const float4*)(b + i);
      float4 v1 = *(const float4*)(b + i + 4);
      r[0] = __fadd_rn(r[0], __fmul_rn(v0.x, v0.x));
      r[1] = __fadd_rn(r[1], __fmul_rn(v0.y, v0.y));
      r[2] = __fadd_rn(r[2], __fmul_rn(v0.z, v0.z));
      r[3] = __fadd_rn(r[3], __fmul_rn(v0.w, v0.w));
      r[4] = __fadd_rn(r[4], __fmul_rn(v1.x, v1.x));
      r[5] = __fadd_rn(r[5], __fmul_rn(v1.y, v1.y));
      r[6] = __fadd_rn(r[6], __fmul_rn(v1.z, v1.z));
      r[7] = __fadd_rn(r[7], __fmul_rn(v1.w, v1.w));
    }
    h[half] = __fadd_rn(
        __fadd_rn(__fadd_rn(r[0], r[1]), __fadd_rn(r[2], r[3])),
        __fadd_rn(__fadd_rn(r[4], r[5]), __fadd_rn(r[6], r[7])));
  }
  return __fadd_rn(h[0], h[1]);
}

__global__ void k_norms(const float* __restrict__ cbw, const float* __restrict__ z,
                        float* __restrict__ cnorm, float* __restrict__ znorm) {
  int r = blockIdx.x * 256 + threadIdx.x;
  if (r < KC) cnorm[r] = np_rownorm256(cbw + (size_t)r * DIM);
  else {
    int q = r - KC;
    if (q < NROWS) znorm[q] = np_rownorm256(z + (size_t)q * DIM);
  }
}

// Build bf16 B-fragment image: frag[ct][ds][lane][8] with
// frag(...)[j] = bf16(cb[ct*32 + (lane&31)][ds*16 + (lane>>5)*8 + j])
__global__ void k_frag(const float* __restrict__ cbw, __bf16* __restrict__ frag) {
  int idx = blockIdx.x * 256 + threadIdx.x;   // 131072 units of 16B
  int c = idx >> 5, u = idx & 31;
  int ds = u >> 1, half = u & 1;
  int ct = c >> 5, m = c & 31;
  int lane = half * 32 + m;
  const float* src = cbw + (size_t)c * DIM + ds * 16 + half * 8;
  float4 a = *(const float4*)src;
  float4 b = *(const float4*)(src + 4);
  bf8 h;
  h[0] = (__bf16)a.x; h[1] = (__bf16)a.y; h[2] = (__bf16)a.z; h[3] = (__bf16)a.w;
  h[4] = (__bf16)b.x; h[5] = (__bf16)b.y; h[6] = (__bf16)b.z; h[7] = (__bf16)b.w;
  *(bf8*)(frag + ((size_t)(ct * 16 + ds) * 64 + lane) * 8) = h;
}

// np-bitwise d2 (validated): sequential fmaf chain, d2 = fl(fl(rn+cn)-fl(2*mm))
__device__ __forceinline__ float exact_d2(const float* __restrict__ zr,
                                          const float* __restrict__ cr,
                                          float rn, float cn) {
  float mm = 0.f;
  for (int d = 0; d < DIM; d += 4) {
    float4 zv = *(const float4*)(zr + d);
    float4 cv = *(const float4*)(cr + d);
    mm = __builtin_fmaf(zv.x, cv.x, mm);
    mm = __builtin_fmaf(zv.y, cv.y, mm);
    mm = __builtin_fmaf(zv.z, cv.z, mm);
    mm = __builtin_fmaf(zv.w, cv.w, mm);
  }
  return __fsub_rn(__fadd_rn(rn, cn), __fmul_rn(2.f, mm));
}

// B-tile load helper (LDS, bf16 elems)
#define BLD(bs, c) (*(const bf8*)((bs) + (c) * 512 + lane * 8))

// A-fragment registers: 16 named bf8 (64 VGPR), hoisted once per kernel
#define AQ_ALL(OP) OP(0) OP(1) OP(2) OP(3) OP(4) OP(5) OP(6) OP(7) \
                   OP(8) OP(9) OP(10) OP(11) OP(12) OP(13) OP(14) OP(15)
#define AQ_DECL(i) const bf8 aq##i = \
  *(const bf8*)&BstA[((size_t)(wr * 16 + (i)) * 64 + lane) * 8];

#define MF(A, B) acc = __builtin_amdgcn_mfma_f32_32x32x16_bf16((A), (B), acc, 0, 0, 0);
#define CONS16(bs_) { \
  __builtin_amdgcn_s_setprio(1); \
  MF(aq0,  BLD(bs_,0))  MF(aq1,  BLD(bs_,1))  MF(aq2,  BLD(bs_,2))  \
  MF(aq3,  BLD(bs_,3))  MF(aq4,  BLD(bs_,4))  MF(aq5,  BLD(bs_,5))  \
  MF(aq6,  BLD(bs_,6))  MF(aq7,  BLD(bs_,7))  MF(aq8,  BLD(bs_,8))  \
  MF(aq9,  BLD(bs_,9))  MF(aq10, BLD(bs_,10)) MF(aq11, BLD(bs_,11)) \
  MF(aq12, BLD(bs_,12)) MF(aq13, BLD(bs_,13)) MF(aq14, BLD(bs_,14)) \
  MF(aq15, BLD(bs_,15)) \
  __builtin_amdgcn_s_setprio(0); }

// 256 threads, 4 waves = 2 row-tiles x 2 streams, 2 blocks/CU (~77 KB LDS).
// R15 = R11 exact revert (best passing: 398.5us total, k_main 331us).
// Closed arcs: register pipelines (RA spills at 64-84 VGPR budget, R1-R3),
// manual per-step vmcnt (R5 catastrophe), L2-traffic reduction (R7/R9 null),
// barrier-count halving (R10 ~null), T15 deferred epilogue (R12 null+spill),
// counted-vmcnt-across-barriers (R13/R14 device faults, mechanism
// unresolved at source level — needs disasm access to pursue safely).
// R11's wins: alias-disambiguated X/Y LDS double-buffers (compiler can keep
// stage loads in flight across the consume) + setprio around MFMA cluster.
__global__ __launch_bounds__(256, 2) void k_main(
    const float* __restrict__ z, const float* __restrict__ cbw,
    const float* __restrict__ cnorm, const float* __restrict__ znorm,
    const __bf16* __restrict__ frag, float* __restrict__ out,
    float* __restrict__ avgp8, double* __restrict__ losssum) {
  // Two DISTINCT double-buffer halves (16 KB per stream each).
  // BstX doubles as the A-stage bounce (32 KB) before the sweep.
  __shared__ __attribute__((aligned(16))) __bf16 BstX[2][8192];        // 32 KB
  __shared__ __attribute__((aligned(16))) __bf16 BstY[2][8192];        // 32 KB
  __shared__ int cand[BM][CAP];                                        // 10 KB
  __shared__ int ccount[BM];
  __shared__ unsigned rowmaxU[BM];                 // running max of e (exp dom)
  __shared__ unsigned long long rowkey[BM];
  __shared__ float esumL[BM], invR[BM], lred[256];
  __shared__ int idxr[BM];

  const int t = threadIdx.x;
  const int lane = t & 63, wv = t >> 6;
  const int ln31 = lane & 31, lh = lane >> 5;
  const int wr = wv >> 1, wc = wv & 1;    // row-tile, column-stream
  const int row0 = blockIdx.x * BM;
  const int ctbase = wc * TPS;

  if (t < BM) {
    ccount[t] = 0; rowmaxU[t] = 0u; rowkey[t] = ~0ULL; esumL[t] = 0.f;
  }

  // ---- stage A (rows 0..63) frag image into BstX cooperatively ----
  __bf16* BstA = &BstX[0][0];
  #pragma unroll
  for (int i = 0; i < 8; ++i) {
    int idx = i * 256 + t;            // 2048 units of 16B
    int l = idx & 63, ds = (idx >> 6) & 15, rt = idx >> 10;
    int row = rt * 32 + (l & 31), d0 = ds * 16 + (l >> 5) * 8;
    const float* src = z + (size_t)(row0 + row) * DIM + d0;
    float4 a = *(const float4*)src;
    float4 b = *(const float4*)(src + 4);
    bf8 h;
    h[0] = (__bf16)a.x; h[1] = (__bf16)a.y; h[2] = (__bf16)a.z; h[3] = (__bf16)a.w;
    h[4] = (__bf16)b.x; h[5] = (__bf16)b.y; h[6] = (__bf16)b.z; h[7] = (__bf16)b.w;
    *(bf8*)&BstA[((size_t)((rt * 16 + ds) * 64 + l)) * 8] = h;
  }
  __syncthreads();

  // ---- hoist A fragments to registers, then BstX/BstY are B buffers ----
  AQ_ALL(AQ_DECL)
  __syncthreads();

  // stage the FULL 16KB B tile ct into ARR[wc]: this wave issues its 8KB
  // share (8 x global_load_lds); the stream's 2 row-waves cover the tile.
  #define STG_A(ARR, ct) { \
    const char* g_ = (const char*)frag + (size_t)(ct) * 16384 + wr * 8192 \
                     + (size_t)lane * 16; \
    char* l_ = (char*)(&ARR[wc][0]) + wr * 8192; \
    GLOAD_LDS(g_, l_);               GLOAD_LDS(g_ + 1024, l_ + 1024); \
    GLOAD_LDS(g_ + 2048, l_ + 2048); GLOAD_LDS(g_ + 3072, l_ + 3072); \
    GLOAD_LDS(g_ + 4096, l_ + 4096); GLOAD_LDS(g_ + 5120, l_ + 5120); \
    GLOAD_LDS(g_ + 6144, l_ + 6144); GLOAD_LDS(g_ + 7168, l_ + 7168); \
  }

  float es[16];
  #pragma unroll
  for (int i = 0; i < 16; ++i) es[i] = 0.f;

  // prime epilogue: seed shared row max (both streams seed each row)
  #define PRIME_EPI(ctv) { \
    const float cnl = cnorm[(ctv) * 32 + ln31] * L2E; \
    _Pragma("unroll") \
    for (int r = 0; r < 16; ++r) { \
      const int row = wr * 32 + (r & 3) + 8 * (r >> 2) + 4 * lh; \
      float e = exp2f(__builtin_fmaf(acc[r], K2L2E, -cnl)); \
      atomicMax(&rowmaxU[row], __float_as_uint(e));  /* e>0: order-preserving */ \
    } \
  }

  // branchless sweep epilogue (validated): snapshot is a lower bound of the
  // true row max -> superset candidate filter; exact rescore fixes all.
  #define SWEEP_EPI(ctv) { \
    const float cnl = cnorm[(ctv) * 32 + ln31] * L2E; \
    float cr[16]; \
    { \
      const float4* rmf = (const float4*)(rowmaxU + wr * 32); \
      float4 c0 = rmf[lh], c1 = rmf[2 + lh], c2 = rmf[4 + lh], c3 = rmf[6 + lh]; \
      cr[0]  = c0.x; cr[1]  = c0.y; cr[2]  = c0.z; cr[3]  = c0.w; \
      cr[4]  = c1.x; cr[5]  = c1.y; cr[6]  = c1.z; cr[7]  = c1.w; \
      cr[8]  = c2.x; cr[9]  = c2.y; cr[10] = c2.z; cr[11] = c2.w; \
      cr[12] = c3.x; cr[13] = c3.y; cr[14] = c3.z; cr[15] = c3.w; \
    } \
    unsigned cond = 0u; \
    _Pragma("unroll") \
    for (int r = 0; r < 16; ++r) { \
      float e = exp2f(__builtin_fmaf(acc[r], K2L2E, -cnl)); \
      es[r] += e;                       /* per-wave sequential fl-chain */ \
      cond |= (e >= cr[r] * KAPPA) ? (1u << r) : 0u; \
    } \
    if (cond) {   /* rare exec-masked slow path: refresh max + insert */ \
      _Pragma("unroll") \
      for (int r = 0; r < 16; ++r) { \
        if (cond & (1u << r)) { \
          const int row = wr * 32 + (r & 3) + 8 * (r >> 2) + 4 * lh; \
          float e = exp2f(__builtin_fmaf(acc[r], K2L2E, -cnl)); \
          atomicMax(&rowmaxU[row], __float_as_uint(e)); \
          int slot = atomicAdd(&ccount[row], 1); \
          if (slot < CAP) cand[row][slot] = (ctv) * 32 + ln31; \
        } \
      } \
    } \
  }

  // one phase-1 tile body: stage next into WRARR, consume RDARR, epilogue, bar
  #define P1BODY(RDARR, WRARR, ctv, ctn, EPI) { \
    STG_A(WRARR, (ctn)) \
    f16v acc; \
    _Pragma("unroll") \
    for (int r = 0; r < 16; ++r) acc[r] = 0.f; \
    CONS16((const __bf16*)&RDARR[wc][0]) \
    EPI((ctv)) \
    __syncthreads(); \
  }

  // ============ Phase 1: prime (c0) + sweep (c1..c64), X/Y alternating ======
  {
    STG_A(BstX, ctbase)               // c0 -> X
    __syncthreads();
    // c0: prime (ct=ctbase), reads X, stages c1 (ct=ctbase) -> Y
    P1BODY(BstX, BstY, ctbase, ctbase, PRIME_EPI)
    // 32 pairs: c_{2p+1} reads Y stages ->X; c_{2p+2} reads X stages ->Y
    for (int p = 0; p < 32; ++p) {
      const int i1 = 2 * p + 1, i2 = 2 * p + 2;
      P1BODY(BstY, BstX, ctbase + i1 - 1, ctbase + i1, SWEEP_EPI)
      {
        const int nx = (i2 < 64) ? ctbase + i2 : ctbase + 63;   // tail: re-stage
        P1BODY(BstX, BstY, ctbase + i2 - 1, nx, SWEEP_EPI)
      }
    }
  }

  // ---- row exp-sum reduction (32 lanes of same half share rows) ----
  #pragma unroll
  for (int r = 0; r < 16; ++r) {
    float e = es[r];
    #pragma unroll
    for (int off = 16; off > 0; off >>= 1) e += __shfl_xor(e, off);
    if (ln31 == 0) {
      const int row = wr * 32 + (r & 3) + 8 * (r >> 2) + 4 * lh;
      atomicAdd(&esumL[row], e);
    }
  }
  __syncthreads();
  if (t < BM) invR[t] = 1.0f / esumL[t];
  __syncthreads();

  // ---- exact np-bitwise rescore of candidates -> argmin (4 threads/row) ----
  {
    int r = t & 63, q = t >> 6;   // q in 0..3
    int cnt = ccount[r];
    const float* zr = z + (size_t)(row0 + r) * DIM;
    float rn = znorm[row0 + r];
    if (cnt <= CAP) {
      for (int s = q; s < cnt; s += 4) {
        int k = cand[r][s];
        float d2 = exact_d2(zr, cbw + (size_t)k * DIM, rn, cnorm[k]);
        atomicMin(&rowkey[r], (((unsigned long long)ford(d2)) << 32) | (unsigned)k);
      }
    } else {  // overflow (improbable): full exact scan, still correct
      for (int k = q; k < KC; k += 4) {
        float d2 = exact_d2(zr, cbw + (size_t)k * DIM, rn, cnorm[k]);
        atomicMin(&rowkey[r], (((unsigned long long)ford(d2)) << 32) | (unsigned)k);
      }
    }
  }
  __syncthreads();
  if (t < BM) {
    int idx = (int)(rowkey[t] & 0xFFFFFFFFULL);
    idxr[t] = idx;
    out[OUT_IDX + row0 + t] = (float)idx;
  }
  __syncthreads();

  // ---- z_q gather, STE output, loss partial (256 threads = 256 cols) ----
  float lacc = 0.f;
  for (int r = 0; r < BM; ++r) {
    int idx = idxr[r];
    float zq = cbw[(size_t)idx * DIM + t];
    float zv = z[(size_t)(row0 + r) * DIM + t];
    float df = __fsub_rn(zq, zv);
    out[(size_t)(row0 + r) * DIM + t] = __fadd_rn(zv, df);
    lacc += df * df;
  }
  lred[t] = lacc;
  __syncthreads();
  #pragma unroll
  for (int s = 128; s > 0; s >>= 1) {
    if (t < s) lred[t] += lred[t + s];
    __syncthreads();
  }
  if (t == 0) atomicAdd(losssum, (double)lred[0]);

  // ---- invR to regs for phase 2 ----
  float ir[16];
  #pragma unroll
  for (int r = 0; r < 16; ++r)
    ir[r] = invR[wr * 32 + (r & 3) + 8 * (r >> 2) + 4 * lh];
  __syncthreads();

  // phase-2 epilogue: avg_probs partial per col
  #define P2EPI(ctv) { \
    const float cnl = cnorm[(ctv) * 32 + ln31] * L2E; \
    float s2 = 0.f; \
    _Pragma("unroll") \
    for (int r = 0; r < 16; ++r) { \
      float e = exp2f(__builtin_fmaf(acc[r], K2L2E, -cnl)); \
      s2 = __builtin_fmaf(e, ir[r], s2); \
    } \
    s2 += __shfl_xor(s2, 32);           /* merge the two lh halves */ \
    if (lh == 0) atomicAdd(&shadow[(ctv) * 32 + ln31], s2); \
  }

  // ============ Phase 2: avg_probs sweep (c0..c63), X/Y alternating ============
  {
    float* shadow = avgp8 + (size_t)(blockIdx.x & 7) * KC;
    STG_A(BstX, ctbase)               // c0 -> X
    __syncthreads();
    for (int p = 0; p < 32; ++p) {
      const int i0 = 2 * p, i1 = 2 * p + 1;
      // c_{i0}: reads X, stages c_{i1} -> Y
      P1BODY(BstX, BstY, ctbase + i0, ctbase + i1, P2EPI)
      // c_{i1}: reads Y, stages c_{i1+1} -> X (tail: re-stage)
      {
        const int nx = (i1 + 1 < 64) ? ctbase + i1 + 1 : ctbase + 63;
        P1BODY(BstY, BstX, ctbase + i1, nx, P2EPI)
      }
    }
  }
}

__global__ void k_final(const float* __restrict__ avgp8,
                        const double* __restrict__ losssum,
                        float* __restrict__ out) {
  const int t = threadIdx.x;
  double part = 0.0;
  for (int k = t; k < KC; k += 256) {
    float a4 = 0.f;
    #pragma unroll
    for (int s = 0; s < 8; ++s) a4 += avgp8[s * KC + k];
    double a = (double)a4 / (double)NROWS;
    part += a * log(a + 1e-10);
  }
  __shared__ double sd[256];
  sd[t] = part;
  __syncthreads();
  for (int s = 128; s > 0; s >>= 1) {
    if (t < s) sd[t] += sd[t + s];
    __syncthreads();
  }
  if (t == 0) {
    double H = -sd[0];
    double mse = losssum[0] / (double)((size_t)NROWS * DIM);
    double ccl = 1.25 * mse;
    double sel = -0.1 * H;
    out[OUT_SCAL + 0] = (float)(ccl + sel);
    out[OUT_SCAL + 1] = (float)ccl;
    out[OUT_SCAL + 2] = (float)sel;
  }
}

extern "C" void kernel_launch(void* const* d_in, const int* in_sizes, int n_in,
                              void* d_out, int out_size, void* d_ws, size_t ws_size,
                              hipStream_t stream) {
  const float* z = (const float*)d_in[0];
  const float* cbw = (const float*)d_in[1];
  float* out = (float*)d_out;
  char* ws = (char*)d_ws;
  float* cnorm = (float*)(ws + WS_CNORM);
  float* znorm = (float*)(ws + WS_ZNORM);
  double* losssum = (double*)(ws + WS_LOSS);
  float* avgp8 = (float*)(ws + WS_AVGP8);
  __bf16* frag = (__bf16*)(ws + WS_FRAG);

  hipMemsetAsync(ws + WS_LOSS, 0, 8, stream);
  hipMemsetAsync(ws + WS_AVGP8, 0, 8 * KC * 4, stream);
  k_norms<<<(KC + NROWS) / 256, 256, 0, stream>>>(cbw, z, cnorm, znorm);
  k_frag<<<(KC * 32) / 256, 256, 0, stream>>>(cbw, frag);
  k_main<<<NROWS / BM, 256, 0, stream>>>(z, cbw, cnorm, znorm, frag, out,
                                         avgp8, losssum);
  k_final<<<1, 256, 0, stream>>>(avgp8, losssum, out);
}

// Round 16
// 387.186 us; speedup vs baseline: 1.0326x; 1.0224x over previous
//
#include <hip/hip_runtime.h>
#include <stdint.h>

// Problem: B=8, L=4096, D=256, K=4096
#define NROWS 32768
#define KC 4096
#define DIM 256
#define BM 64            // rows per block (2 row-tiles of 32)
#define TPS 64           // col-tiles per stream (2 streams x 64 = 128)
#define CAP 40
#define KAPPA 0.99960f   // exp(-margin), margin 4e-4 > validated 3e-4
#define K2L2E 2.88539008f // 2*log2(e)
#define L2E 1.44269504f

#define OUT_IDX (NROWS * DIM)
#define OUT_SCAL (OUT_IDX + NROWS)

// Workspace layout (bytes)
#define WS_CNORM 0
#define WS_ZNORM 16384                   // unused since R16 (znorm in k_main)
#define WS_LOSS  147456
#define WS_AVGP8 147712                  // 8 shadows x 4096 f32 = 128 KB
#define WS_FRAG  278784                  // bf16 fragment image, 2 MB

typedef __bf16 bf8 __attribute__((ext_vector_type(8)));
typedef float f16v __attribute__((ext_vector_type(16)));

// async global->LDS, 16B per lane; LDS dest = wave-uniform base + lane*16
#define GLOAD_LDS(g, l) \
  __builtin_amdgcn_global_load_lds( \
      (const __attribute__((address_space(1))) void*)(g), \
      (__attribute__((address_space(3))) void*)(l), 16, 0, 0)

// monotonic float->uint order map (argmin with first-index tie-break)
__device__ __forceinline__ unsigned ford(float f) {
  unsigned u = __float_as_uint(f);
  return (u & 0x80000000u) ? ~u : (u | 0x80000000u);
}

// numpy pairwise-sum of x**2 (n=256), bitwise == np.sum(x**2).
// Same arithmetic/order as the validated scalar version; loads via float4.
__device__ __forceinline__ float np_rownorm256(const float* __restrict__ p) {
  float h[2];
  #pragma unroll
  for (int half = 0; half < 2; ++half) {
    const float* b = p + half * 128;
    float r[8];
    {
      float4 v0 = *(const float4*)(b);
      float4 v1 = *(const float4*)(b + 4);
      r[0] = __fmul_rn(v0.x, v0.x); r[1] = __fmul_rn(v0.y, v0.y);
      r[2] = __fmul_rn(v0.z, v0.z); r[3] = __fmul_rn(v0.w, v0.w);
      r[4] = __fmul_rn(v1.x, v1.x); r[5] = __fmul_rn(v1.y, v1.y);
      r[6] = __fmul_rn(v1.z, v1.z); r[7] = __fmul_rn(v1.w, v1.w);
    }
    for (int i = 8; i < 128; i += 8) {
      float4 v0 = *(const float4*)(b + i);
      float4 v1 = *(const float4*)(b + i + 4);
      r[0] = __fadd_rn(r[0], __fmul_rn(v0.x, v0.x));
      r[1] = __fadd_rn(r[1], __fmul_rn(v0.y, v0.y));
      r[2] = __fadd_rn(r[2], __fmul_rn(v0.z, v0.z));
      r[3] = __fadd_rn(r[3], __fmul_rn(v0.w, v0.w));
      r[4] = __fadd_rn(r[4], __fmul_rn(v1.x, v1.x));
      r[5] = __fadd_rn(r[5], __fmul_rn(v1.y, v1.y));
      r[6] = __fadd_rn(r[6], __fmul_rn(v1.z, v1.z));
      r[7] = __fadd_rn(r[7], __fmul_rn(v1.w, v1.w));
    }
    h[half] = __fadd_rn(
        __fadd_rn(__fadd_rn(r[0], r[1]), __fadd_rn(r[2], r[3])),
        __fadd_rn(__fadd_rn(r[4], r[5]), __fadd_rn(r[6], r[7])));
  }
  return __fadd_rn(h[0], h[1]);
}

// Fused prep (R16): blocks 0..511 build the bf16 B-fragment image (was
// k_frag); blocks 512..527 compute cnorm AND zero avgp8/losssum (was
// k_norms' cnorm half + the two hipMemsetAsync). znorm moved into k_main
// (bitwise-identical np_rownorm256 on the same rows, L2-hot there).
// frag[ct][ds][lane][8]: frag(...)[j] = bf16(cb[ct*32+(lane&31)][ds*16+(lane>>5)*8+j])
__global__ void k_prep(const float* __restrict__ cbw, __bf16* __restrict__ frag,
                       float* __restrict__ cnorm, float* __restrict__ avgp8,
                       double* __restrict__ losssum) {
  const int b = blockIdx.x;
  if (b < 512) {
    int idx = b * 256 + threadIdx.x;   // 131072 units of 16B
    int c = idx >> 5, u = idx & 31;
    int ds = u >> 1, half = u & 1;
    int ct = c >> 5, m = c & 31;
    int lane = half * 32 + m;
    const float* src = cbw + (size_t)c * DIM + ds * 16 + half * 8;
    float4 a = *(const float4*)src;
    float4 bb = *(const float4*)(src + 4);
    bf8 h;
    h[0] = (__bf16)a.x;  h[1] = (__bf16)a.y;  h[2] = (__bf16)a.z;  h[3] = (__bf16)a.w;
    h[4] = (__bf16)bb.x; h[5] = (__bf16)bb.y; h[6] = (__bf16)bb.z; h[7] = (__bf16)bb.w;
    *(bf8*)(frag + ((size_t)(ct * 16 + ds) * 64 + lane) * 8) = h;
  } else {
    const int q = b - 512;             // 0..15
    int r = q * 256 + threadIdx.x;     // 0..4095
    cnorm[r] = np_rownorm256(cbw + (size_t)r * DIM);
    // zero the 8 avgp8 shadows: 16 blocks x 256 threads x 8 = 32768 floats
    float* ap = avgp8 + (size_t)q * 2048 + threadIdx.x;
    #pragma unroll
    for (int i = 0; i < 8; ++i) ap[i * 256] = 0.f;
    if (q == 0 && threadIdx.x == 0) *losssum = 0.0;
  }
}

// np-bitwise d2 (validated): sequential fmaf chain, d2 = fl(fl(rn+cn)-fl(2*mm))
__device__ __forceinline__ float exact_d2(const float* __restrict__ zr,
                                          const float* __restrict__ cr,
                                          float rn, float cn) {
  float mm = 0.f;
  for (int d = 0; d < DIM; d += 4) {
    float4 zv = *(const float4*)(zr + d);
    float4 cv = *(const float4*)(cr + d);
    mm = __builtin_fmaf(zv.x, cv.x, mm);
    mm = __builtin_fmaf(zv.y, cv.y, mm);
    mm = __builtin_fmaf(zv.z, cv.z, mm);
    mm = __builtin_fmaf(zv.w, cv.w, mm);
  }
  return __fsub_rn(__fadd_rn(rn, cn), __fmul_rn(2.f, mm));
}

// B-tile load helper (LDS, bf16 elems)
#define BLD(bs, c) (*(const bf8*)((bs) + (c) * 512 + lane * 8))

// A-fragment registers: 16 named bf8 (64 VGPR), hoisted once per kernel
#define AQ_ALL(OP) OP(0) OP(1) OP(2) OP(3) OP(4) OP(5) OP(6) OP(7) \
                   OP(8) OP(9) OP(10) OP(11) OP(12) OP(13) OP(14) OP(15)
#define AQ_DECL(i) const bf8 aq##i = \
  *(const bf8*)&BstA[((size_t)(wr * 16 + (i)) * 64 + lane) * 8];

#define MF(A, B) acc = __builtin_amdgcn_mfma_f32_32x32x16_bf16((A), (B), acc, 0, 0, 0);
#define CONS16(bs_) { \
  __builtin_amdgcn_s_setprio(1); \
  MF(aq0,  BLD(bs_,0))  MF(aq1,  BLD(bs_,1))  MF(aq2,  BLD(bs_,2))  \
  MF(aq3,  BLD(bs_,3))  MF(aq4,  BLD(bs_,4))  MF(aq5,  BLD(bs_,5))  \
  MF(aq6,  BLD(bs_,6))  MF(aq7,  BLD(bs_,7))  MF(aq8,  BLD(bs_,8))  \
  MF(aq9,  BLD(bs_,9))  MF(aq10, BLD(bs_,10)) MF(aq11, BLD(bs_,11)) \
  MF(aq12, BLD(bs_,12)) MF(aq13, BLD(bs_,13)) MF(aq14, BLD(bs_,14)) \
  MF(aq15, BLD(bs_,15)) \
  __builtin_amdgcn_s_setprio(0); }

// 256 threads, 4 waves = 2 row-tiles x 2 streams, 2 blocks/CU (~77 KB LDS).
// R16 = R11/R15 k_main (best passing: k_main 323us) + znorm computed
// in-block (rows are L1/L2-hot right after the A-stage) — bitwise-identical
// np_rownorm256 -> identical rescore. Aux launches fused into k_prep.
__global__ __launch_bounds__(256, 2) void k_main(
    const float* __restrict__ z, const float* __restrict__ cbw,
    const float* __restrict__ cnorm,
    const __bf16* __restrict__ frag, float* __restrict__ out,
    float* __restrict__ avgp8, double* __restrict__ losssum) {
  // Two DISTINCT double-buffer halves (16 KB per stream each).
  // BstX doubles as the A-stage bounce (32 KB) before the sweep.
  __shared__ __attribute__((aligned(16))) __bf16 BstX[2][8192];        // 32 KB
  __shared__ __attribute__((aligned(16))) __bf16 BstY[2][8192];        // 32 KB
  __shared__ int cand[BM][CAP];                                        // 10 KB
  __shared__ int ccount[BM];
  __shared__ unsigned rowmaxU[BM];                 // running max of e (exp dom)
  __shared__ unsigned long long rowkey[BM];
  __shared__ float esumL[BM], invR[BM], lred[256];
  __shared__ float znormL[BM];                     // per-block row norms (R16)
  __shared__ int idxr[BM];

  const int t = threadIdx.x;
  const int lane = t & 63, wv = t >> 6;
  const int ln31 = lane & 31, lh = lane >> 5;
  const int wr = wv >> 1, wc = wv & 1;    // row-tile, column-stream
  const int row0 = blockIdx.x * BM;
  const int ctbase = wc * TPS;

  if (t < BM) {
    ccount[t] = 0; rowmaxU[t] = 0u; rowkey[t] = ~0ULL; esumL[t] = 0.f;
  }

  // ---- stage A (rows 0..63) frag image into BstX cooperatively ----
  __bf16* BstA = &BstX[0][0];
  #pragma unroll
  for (int i = 0; i < 8; ++i) {
    int idx = i * 256 + t;            // 2048 units of 16B
    int l = idx & 63, ds = (idx >> 6) & 15, rt = idx >> 10;
    int row = rt * 32 + (l & 31), d0 = ds * 16 + (l >> 5) * 8;
    const float* src = z + (size_t)(row0 + row) * DIM + d0;
    float4 a = *(const float4*)src;
    float4 b = *(const float4*)(src + 4);
    bf8 h;
    h[0] = (__bf16)a.x; h[1] = (__bf16)a.y; h[2] = (__bf16)a.z; h[3] = (__bf16)a.w;
    h[4] = (__bf16)b.x; h[5] = (__bf16)b.y; h[6] = (__bf16)b.z; h[7] = (__bf16)b.w;
    *(bf8*)&BstA[((size_t)((rt * 16 + ds) * 64 + l)) * 8] = h;
  }
  // ---- znorm for this block's 64 rows (R16): same np_rownorm256 bits as
  // the old k_norms; rows were just read above -> L1/L2-hot ----
  if (t < BM) znormL[t] = np_rownorm256(z + (size_t)(row0 + t) * DIM);
  __syncthreads();

  // ---- hoist A fragments to registers, then BstX/BstY are B buffers ----
  AQ_ALL(AQ_DECL)
  __syncthreads();

  // stage the FULL 16KB B tile ct into ARR[wc]: this wave issues its 8KB
  // share (8 x global_load_lds); the stream's 2 row-waves cover the tile.
  #define STG_A(ARR, ct) { \
    const char* g_ = (const char*)frag + (size_t)(ct) * 16384 + wr * 8192 \
                     + (size_t)lane * 16; \
    char* l_ = (char*)(&ARR[wc][0]) + wr * 8192; \
    GLOAD_LDS(g_, l_);               GLOAD_LDS(g_ + 1024, l_ + 1024); \
    GLOAD_LDS(g_ + 2048, l_ + 2048); GLOAD_LDS(g_ + 3072, l_ + 3072); \
    GLOAD_LDS(g_ + 4096, l_ + 4096); GLOAD_LDS(g_ + 5120, l_ + 5120); \
    GLOAD_LDS(g_ + 6144, l_ + 6144); GLOAD_LDS(g_ + 7168, l_ + 7168); \
  }

  float es[16];
  #pragma unroll
  for (int i = 0; i < 16; ++i) es[i] = 0.f;

  // prime epilogue: seed shared row max (both streams seed each row)
  #define PRIME_EPI(ctv) { \
    const float cnl = cnorm[(ctv) * 32 + ln31] * L2E; \
    _Pragma("unroll") \
    for (int r = 0; r < 16; ++r) { \
      const int row = wr * 32 + (r & 3) + 8 * (r >> 2) + 4 * lh; \
      float e = exp2f(__builtin_fmaf(acc[r], K2L2E, -cnl)); \
      atomicMax(&rowmaxU[row], __float_as_uint(e));  /* e>0: order-preserving */ \
    } \
  }

  // branchless sweep epilogue (validated): snapshot is a lower bound of the
  // true row max -> superset candidate filter; exact rescore fixes all.
  #define SWEEP_EPI(ctv) { \
    const float cnl = cnorm[(ctv) * 32 + ln31] * L2E; \
    float cr[16]; \
    { \
      const float4* rmf = (const float4*)(rowmaxU + wr * 32); \
      float4 c0 = rmf[lh], c1 = rmf[2 + lh], c2 = rmf[4 + lh], c3 = rmf[6 + lh]; \
      cr[0]  = c0.x; cr[1]  = c0.y; cr[2]  = c0.z; cr[3]  = c0.w; \
      cr[4]  = c1.x; cr[5]  = c1.y; cr[6]  = c1.z; cr[7]  = c1.w; \
      cr[8]  = c2.x; cr[9]  = c2.y; cr[10] = c2.z; cr[11] = c2.w; \
      cr[12] = c3.x; cr[13] = c3.y; cr[14] = c3.z; cr[15] = c3.w; \
    } \
    unsigned cond = 0u; \
    _Pragma("unroll") \
    for (int r = 0; r < 16; ++r) { \
      float e = exp2f(__builtin_fmaf(acc[r], K2L2E, -cnl)); \
      es[r] += e;                       /* per-wave sequential fl-chain */ \
      cond |= (e >= cr[r] * KAPPA) ? (1u << r) : 0u; \
    } \
    if (cond) {   /* rare exec-masked slow path: refresh max + insert */ \
      _Pragma("unroll") \
      for (int r = 0; r < 16; ++r) { \
        if (cond & (1u << r)) { \
          const int row = wr * 32 + (r & 3) + 8 * (r >> 2) + 4 * lh; \
          float e = exp2f(__builtin_fmaf(acc[r], K2L2E, -cnl)); \
          atomicMax(&rowmaxU[row], __float_as_uint(e)); \
          int slot = atomicAdd(&ccount[row], 1); \
          if (slot < CAP) cand[row][slot] = (ctv) * 32 + ln31; \
        } \
      } \
    } \
  }

  // one phase-1 tile body: stage next into WRARR, consume RDARR, epilogue, bar
  #define P1BODY(RDARR, WRARR, ctv, ctn, EPI) { \
    STG_A(WRARR, (ctn)) \
    f16v acc; \
    _Pragma("unroll") \
    for (int r = 0; r < 16; ++r) acc[r] = 0.f; \
    CONS16((const __bf16*)&RDARR[wc][0]) \
    EPI((ctv)) \
    __syncthreads(); \
  }

  // ============ Phase 1: prime (c0) + sweep (c1..c64), X/Y alternating ======
  {
    STG_A(BstX, ctbase)               // c0 -> X
    __syncthreads();
    // c0: prime (ct=ctbase), reads X, stages c1 (ct=ctbase) -> Y
    P1BODY(BstX, BstY, ctbase, ctbase, PRIME_EPI)
    // 32 pairs: c_{2p+1} reads Y stages ->X; c_{2p+2} reads X stages ->Y
    for (int p = 0; p < 32; ++p) {
      const int i1 = 2 * p + 1, i2 = 2 * p + 2;
      P1BODY(BstY, BstX, ctbase + i1 - 1, ctbase + i1, SWEEP_EPI)
      {
        const int nx = (i2 < 64) ? ctbase + i2 : ctbase + 63;   // tail: re-stage
        P1BODY(BstX, BstY, ctbase + i2 - 1, nx, SWEEP_EPI)
      }
    }
  }

  // ---- row exp-sum reduction (32 lanes of same half share rows) ----
  #pragma unroll
  for (int r = 0; r < 16; ++r) {
    float e = es[r];
    #pragma unroll
    for (int off = 16; off > 0; off >>= 1) e += __shfl_xor(e, off);
    if (ln31 == 0) {
      const int row = wr * 32 + (r & 3) + 8 * (r >> 2) + 4 * lh;
      atomicAdd(&esumL[row], e);
    }
  }
  __syncthreads();
  if (t < BM) invR[t] = 1.0f / esumL[t];
  __syncthreads();

  // ---- exact np-bitwise rescore of candidates -> argmin (4 threads/row) ----
  {
    int r = t & 63, q = t >> 6;   // q in 0..3
    int cnt = ccount[r];
    const float* zr = z + (size_t)(row0 + r) * DIM;
    float rn = znormL[r];
    if (cnt <= CAP) {
      for (int s = q; s < cnt; s += 4) {
        int k = cand[r][s];
        float d2 = exact_d2(zr, cbw + (size_t)k * DIM, rn, cnorm[k]);
        atomicMin(&rowkey[r], (((unsigned long long)ford(d2)) << 32) | (unsigned)k);
      }
    } else {  // overflow (improbable): full exact scan, still correct
      for (int k = q; k < KC; k += 4) {
        float d2 = exact_d2(zr, cbw + (size_t)k * DIM, rn, cnorm[k]);
        atomicMin(&rowkey[r], (((unsigned long long)ford(d2)) << 32) | (unsigned)k);
      }
    }
  }
  __syncthreads();
  if (t < BM) {
    int idx = (int)(rowkey[t] & 0xFFFFFFFFULL);
    idxr[t] = idx;
    out[OUT_IDX + row0 + t] = (float)idx;
  }
  __syncthreads();

  // ---- z_q gather, STE output, loss partial (256 threads = 256 cols) ----
  float lacc = 0.f;
  for (int r = 0; r < BM; ++r) {
    int idx = idxr[r];
    float zq = cbw[(size_t)idx * DIM + t];
    float zv = z[(size_t)(row0 + r) * DIM + t];
    float df = __fsub_rn(zq, zv);
    out[(size_t)(row0 + r) * DIM + t] = __fadd_rn(zv, df);
    lacc += df * df;
  }
  lred[t] = lacc;
  __syncthreads();
  #pragma unroll
  for (int s = 128; s > 0; s >>= 1) {
    if (t < s) lred[t] += lred[t + s];
    __syncthreads();
  }
  if (t == 0) atomicAdd(losssum, (double)lred[0]);

  // ---- invR to regs for phase 2 ----
  float ir[16];
  #pragma unroll
  for (int r = 0; r < 16; ++r)
    ir[r] = invR[wr * 32 + (r & 3) + 8 * (r >> 2) + 4 * lh];
  __syncthreads();

  // phase-2 epilogue: avg_probs partial per col
  #define P2EPI(ctv) { \
    const float cnl = cnorm[(ctv) * 32 + ln31] * L2E; \
    float s2 = 0.f; \
    _Pragma("unroll") \
    for (int r = 0; r < 16; ++r) { \
      float e = exp2f(__builtin_fmaf(acc[r], K2L2E, -cnl)); \
      s2 = __builtin_fmaf(e, ir[r], s2); \
    } \
    s2 += __shfl_xor(s2, 32);           /* merge the two lh halves */ \
    if (lh == 0) atomicAdd(&shadow[(ctv) * 32 + ln31], s2); \
  }

  // ============ Phase 2: avg_probs sweep (c0..c63), X/Y alternating ============
  {
    float* shadow = avgp8 + (size_t)(blockIdx.x & 7) * KC;
    STG_A(BstX, ctbase)               // c0 -> X
    __syncthreads();
    for (int p = 0; p < 32; ++p) {
      const int i0 = 2 * p, i1 = 2 * p + 1;
      // c_{i0}: reads X, stages c_{i1} -> Y
      P1BODY(BstX, BstY, ctbase + i0, ctbase + i1, P2EPI)
      // c_{i1}: reads Y, stages c_{i1+1} -> X (tail: re-stage)
      {
        const int nx = (i1 + 1 < 64) ? ctbase + i1 + 1 : ctbase + 63;
        P1BODY(BstY, BstX, ctbase + i1, nx, P2EPI)
      }
    }
  }
}

__global__ void k_final(const float* __restrict__ avgp8,
                        const double* __restrict__ losssum,
                        float* __restrict__ out) {
  const int t = threadIdx.x;
  double part = 0.0;
  for (int k = t; k < KC; k += 256) {
    float a4 = 0.f;
    #pragma unroll
    for (int s = 0; s < 8; ++s) a4 += avgp8[s * KC + k];
    double a = (double)a4 / (double)NROWS;
    part += a * log(a + 1e-10);
  }
  __shared__ double sd[256];
  sd[t] = part;
  __syncthreads();
  for (int s = 128; s > 0; s >>= 1) {
    if (t < s) sd[t] += sd[t + s];
    __syncthreads();
  }
  if (t == 0) {
    double H = -sd[0];
    double mse = losssum[0] / (double)((size_t)NROWS * DIM);
    double ccl = 1.25 * mse;
    double sel = -0.1 * H;
    out[OUT_SCAL + 0] = (float)(ccl + sel);
    out[OUT_SCAL + 1] = (float)ccl;
    out[OUT_SCAL + 2] = (float)sel;
  }
}

extern "C" void kernel_launch(void* const* d_in, const int* in_sizes, int n_in,
                              void* d_out, int out_size, void* d_ws, size_t ws_size,
                              hipStream_t stream) {
  const float* z = (const float*)d_in[0];
  const float* cbw = (const float*)d_in[1];
  float* out = (float*)d_out;
  char* ws = (char*)d_ws;
  float* cnorm = (float*)(ws + WS_CNORM);
  double* losssum = (double*)(ws + WS_LOSS);
  float* avgp8 = (float*)(ws + WS_AVGP8);
  __bf16* frag = (__bf16*)(ws + WS_FRAG);

  // R16: fused prep (frag build + cnorm + avgp8/losssum zeroing) replaces
  // k_norms + k_frag + 2x hipMemsetAsync; znorm computed inside k_main.
  k_prep<<<528, 256, 0, stream>>>(cbw, frag, cnorm, avgp8, losssum);
  k_main<<<NROWS / BM, 256, 0, stream>>>(z, cbw, cnorm, frag, out,
                                         avgp8, losssum);
  k_final<<<1, 256, 0, stream>>>(avgp8, losssum, out);
}